// Round 6
// baseline (372.390 us; speedup 1.0000x reference)
//
#include <hip/hip_runtime.h>
#include <math.h>

namespace {
constexpr int   kB        = 8192;
constexpr int   kBlock    = 256;
constexpr int   kRows     = 8;
constexpr int   kGrid     = kB / kRows;   // 1024 blocks = 4/CU
constexpr float kMargin   = 0.1f;
constexpr float kThresh   = 0.5f;
constexpr float kScalePos = 2.0f;
constexpr float kScaleNeg = 40.0f;
constexpr float kEps      = 1e-5f;
}

// R9: break the convoy, take 2. R8's LDS spin barrier hit a gfx950 backend
// bug (generic-pointer null-check against src_shared_base miscompiles). The
// spin was never needed: the vmcnt(0) drain at __syncthreads is COMPILER
// semantics, not s_barrier hardware. Raw __builtin_amdgcn_s_barrier() +
// lgkmcnt(0)-only waits (the HipKittens pattern, learn_hip m139) lets the
// next row's 8 dwordx4 prefetch stay in flight through both compute passes.
// Also restores R6's register pin on the current buffer right after the
// prefetch issue: forces a COUNTED vmcnt(8) wait for CUR (prefetch stays
// outstanding) and makes CUR un-rematerializable in pass 2 (R5's failure).
__global__ __launch_bounds__(kBlock, 4) void ms_loss_kernel(
    const float* __restrict__ sim,
    const int*   __restrict__ labels,
    float*       __restrict__ ws,      // nullptr -> atomic fallback
    float*       __restrict__ out)
{
  const int tid  = threadIdx.x;
  const int wave = tid >> 6;
  const int lane = tid & 63;
  const int base = blockIdx.x * kRows;

  __shared__ float s_min[4], s_max[4], s_pos[4], s_neg[4];

  // ---- Own-column labels, packed 2x16 bits (labels < 1024) -> 16 VGPRs ----
  unsigned int lab16[16];
  #pragma unroll
  for (int k = 0; k < 8; ++k) {
    const int4 L = *reinterpret_cast<const int4*>(labels + k * 1024 + tid * 4);
    lab16[2 * k + 0] = ((unsigned)L.x & 0xFFFFu) | ((unsigned)L.y << 16);
    lab16[2 * k + 1] = ((unsigned)L.z & 0xFFFFu) | ((unsigned)L.w << 16);
  }
  int ml[kRows];
  #pragma unroll
  for (int r = 0; r < kRows; ++r) ml[r] = labels[base + r];   // uniform -> s_load

  // ---- Prologue: row 0 into bufA ----
  float4 bufA[8], bufB[8];
  {
    const float* __restrict__ s0 = sim + (size_t)base * kB;
    #pragma unroll
    for (int k = 0; k < 8; ++k)
      bufA[k] = *reinterpret_cast<const float4*>(s0 + k * 1024 + tid * 4);
  }

// Raw barrier: LDS-write visibility only (lgkmcnt), NO vmcnt drain -> the
// prefetch loads stay in flight across it. Trailing memory-clobber fence
// stops LDS reads from hoisting above the barrier (rule #18 analog).
#define BAR()                                                                  \
  {                                                                            \
    asm volatile("s_waitcnt lgkmcnt(0)" ::: "memory");                         \
    __builtin_amdgcn_s_barrier();                                              \
    asm volatile("" ::: "memory");                                             \
  }

#define ROW_BODY(CUR, NXT, R, PREFETCH)                                        \
  {                                                                            \
    if (PREFETCH) {                                                            \
      const float* __restrict__ sp = sim + (size_t)(base + (R) + 1) * kB;      \
      _Pragma("unroll")                                                        \
      for (int k = 0; k < 8; ++k)                                              \
        NXT[k] = *reinterpret_cast<const float4*>(sp + k * 1024 + tid * 4);    \
      __builtin_amdgcn_sched_barrier(0);  /* pin prefetch issue point */       \
    }                                                                          \
    /* Pin CUR: counted vmcnt wait (prefetch stays outstanding) + no remat */  \
    _Pragma("unroll")                                                          \
    for (int k = 0; k < 8; ++k)                                                \
      asm volatile("" : "+v"(CUR[k].x), "+v"(CUR[k].y),                        \
                         "+v"(CUR[k].z), "+v"(CUR[k].w));                      \
    const unsigned int mlr = (unsigned)ml[R];                                  \
    unsigned int msk = 0;                                                      \
    _Pragma("unroll")                                                          \
    for (int j = 0; j < 16; ++j) {                                             \
      msk |= (unsigned)((lab16[j] & 0xFFFFu) == mlr) << (2 * j);               \
      msk |= (unsigned)((lab16[j] >> 16) == mlr) << (2 * j + 1);               \
    }                                                                          \
    float min_pos = INFINITY, max_neg = -INFINITY;                             \
    _Pragma("unroll")                                                          \
    for (int k = 0; k < 8; ++k) {                                              \
      const float xs[4] = {CUR[k].x, CUR[k].y, CUR[k].z, CUR[k].w};            \
      _Pragma("unroll")                                                        \
      for (int c = 0; c < 4; ++c) {                                            \
        const bool  same = (msk >> (k * 4 + c)) & 1u;                          \
        const float x = xs[c];                                                 \
        min_pos = fminf(min_pos, (same && x < 1.0f - kEps) ? x : INFINITY);    \
        max_neg = fmaxf(max_neg, same ? -INFINITY : x);                        \
      }                                                                        \
    }                                                                          \
    _Pragma("unroll")                                                          \
    for (int off = 32; off > 0; off >>= 1) {                                   \
      min_pos = fminf(min_pos, __shfl_xor(min_pos, off, 64));                  \
      max_neg = fmaxf(max_neg, __shfl_xor(max_neg, off, 64));                  \
    }                                                                          \
    if (lane == 0) { s_min[wave] = min_pos; s_max[wave] = max_neg; }           \
    BAR();                                                                     \
    min_pos = fminf(fminf(s_min[0], s_min[1]), fminf(s_min[2], s_min[3]));     \
    max_neg = fmaxf(fmaxf(s_max[0], s_max[1]), fmaxf(s_max[2], s_max[3]));     \
    float pos_sum = 0.0f, neg_sum = 0.0f;                                      \
    _Pragma("unroll")                                                          \
    for (int k = 0; k < 8; ++k) {                                              \
      const float xs[4] = {CUR[k].x, CUR[k].y, CUR[k].z, CUR[k].w};            \
      _Pragma("unroll")                                                        \
      for (int c = 0; c < 4; ++c) {                                            \
        const bool  same = (msk >> (k * 4 + c)) & 1u;                          \
        const float x = xs[c];                                                 \
        const float a = same ? -kScalePos : kScaleNeg;                         \
        const float e = __expf(a * (x - kThresh));                             \
        const bool selp = same && (x < 1.0f - kEps) && (x - kMargin < max_neg);\
        const bool seln = (!same) && (x + kMargin > min_pos);                  \
        pos_sum += selp ? e : 0.0f;                                            \
        neg_sum += seln ? e : 0.0f;                                            \
      }                                                                        \
    }                                                                          \
    _Pragma("unroll")                                                          \
    for (int off = 32; off > 0; off >>= 1) {                                   \
      pos_sum += __shfl_xor(pos_sum, off, 64);                                 \
      neg_sum += __shfl_xor(neg_sum, off, 64);                                 \
    }                                                                          \
    if (lane == 0) { s_pos[wave] = pos_sum; s_neg[wave] = neg_sum; }           \
    BAR();                                                                     \
    if (tid == 0) {                                                            \
      const float ps = (s_pos[0] + s_pos[1]) + (s_pos[2] + s_pos[3]);          \
      const float ns = (s_neg[0] + s_neg[1]) + (s_neg[2] + s_neg[3]);          \
      const bool  valid = (ps > 0.0f) && (ns > 0.0f);                          \
      const float rl = valid ? (log1pf(ps) * (1.0f / kScalePos)                \
                              + log1pf(ns) * (1.0f / kScaleNeg)) : 0.0f;       \
      if (ws) ws[base + (R)] = rl;                                             \
      else if (rl != 0.0f) atomicAdd(out, rl * (1.0f / (float)kB));            \
    }                                                                          \
    BAR();  /* s_min/s_max reuse fence for next row */                         \
  }

  ROW_BODY(bufA, bufB, 0, true);
  ROW_BODY(bufB, bufA, 1, true);
  ROW_BODY(bufA, bufB, 2, true);
  ROW_BODY(bufB, bufA, 3, true);
  ROW_BODY(bufA, bufB, 4, true);
  ROW_BODY(bufB, bufA, 5, true);
  ROW_BODY(bufA, bufB, 6, true);
  ROW_BODY(bufB, bufA, 7, false);

#undef ROW_BODY
#undef BAR
}

// Sums ws[0..8191], scales by 1/B, writes out[0]. One block, ~32KB L2 read.
__global__ __launch_bounds__(256) void ms_reduce_kernel(
    const float* __restrict__ ws,
    float*       __restrict__ out)
{
  const int tid = threadIdx.x;
  float s = 0.0f;
  #pragma unroll
  for (int k = 0; k < 8; ++k) {
    const float4 f = *reinterpret_cast<const float4*>(ws + k * 1024 + tid * 4);
    s += (f.x + f.y) + (f.z + f.w);
  }
  #pragma unroll
  for (int off = 32; off > 0; off >>= 1)
    s += __shfl_xor(s, off, 64);
  __shared__ float sm[4];
  if ((tid & 63) == 0) sm[tid >> 6] = s;
  __syncthreads();
  if (tid == 0)
    out[0] = ((sm[0] + sm[1]) + (sm[2] + sm[3])) * (1.0f / (float)kB);
}

extern "C" void kernel_launch(void* const* d_in, const int* in_sizes, int n_in,
                              void* d_out, int out_size, void* d_ws, size_t ws_size,
                              hipStream_t stream) {
  const float* sim    = (const float*)d_in[0];
  const int*   labels = (const int*)d_in[1];
  float*       out    = (float*)d_out;

  // d_out is re-poisoned to 0xAA before every timed launch — zero it here.
  hipMemsetAsync(d_out, 0, sizeof(float) * (size_t)out_size, stream);

  if (d_ws != nullptr && ws_size >= (size_t)kB * sizeof(float)) {
    float* ws = (float*)d_ws;
    ms_loss_kernel<<<dim3(kGrid), dim3(kBlock), 0, stream>>>(sim, labels, ws, out);
    ms_reduce_kernel<<<dim3(1), dim3(256), 0, stream>>>(ws, out);
  } else {
    ms_loss_kernel<<<dim3(kGrid), dim3(kBlock), 0, stream>>>(sim, labels, nullptr, out);
  }
}